// Round 9
// baseline (268.158 us; speedup 1.0000x reference)
//
#include <hip/hip_runtime.h>
#include <hip/hip_bf16.h>

typedef __bf16 bf16x8 __attribute__((ext_vector_type(8)));
typedef float f32x4 __attribute__((ext_vector_type(4)));
typedef float f32x16 __attribute__((ext_vector_type(16)));
typedef unsigned short us8 __attribute__((ext_vector_type(8)));

#define NLOG2E  -1.44269504088896340736f
#define TWOLOG2E 2.88539008177792681472f

__device__ __forceinline__ unsigned short f2bf(float f) {
    unsigned u = __float_as_uint(f);
    u += 0x7fffu + ((u >> 16) & 1u);   // round-to-nearest-even
    return (unsigned short)(u >> 16);
}

// ---- prep: fp32 -> bf16 in MFMA-fragment panel order + pre-scaled row norms.
// Panel layout (per 32 rows): byte = panel*8192 + kk*1024 + hi*512 + (row&31)*16,
// holding k in [16*kk + 8*hi, +8). A wave's fragment load is then base + kk*1024 + l*16
// (since l*16 == (l>>5)*512 + (l&31)*16): fully coalesced 1KB register loads. ----
__global__ __launch_bounds__(256)
void rbf_prep(const float* __restrict__ X, const float* __restrict__ Y,
              char* __restrict__ Xp, char* __restrict__ Yp,
              float* __restrict__ x2n, float* __restrict__ y2n) {
    const int b = blockIdx.x;                  // 0..255 -> X, 256..511 -> Y
    const float* src = (b < 256) ? X : Y;
    char* db = (b < 256) ? Xp : Yp;
    float* dn = (b < 256) ? x2n : y2n;
    const int p = b & 255;                     // 32-row panel index
    const int r0 = p * 32;
    const int t = threadIdx.x;

    // convert: thread (ln = t&31, s = t>>5) handles row r0+ln, floats [16s, 16s+16)
    {
        const int ln = t & 31, s = t >> 5;
        const f32x4* row = (const f32x4*)(src + (size_t)(r0 + ln) * 128);
        f32x4 v0 = row[s * 4 + 0], v1 = row[s * 4 + 1];
        f32x4 v2 = row[s * 4 + 2], v3 = row[s * 4 + 3];
        us8 lo, hh;
        lo[0] = f2bf(v0[0]); lo[1] = f2bf(v0[1]); lo[2] = f2bf(v0[2]); lo[3] = f2bf(v0[3]);
        lo[4] = f2bf(v1[0]); lo[5] = f2bf(v1[1]); lo[6] = f2bf(v1[2]); lo[7] = f2bf(v1[3]);
        hh[0] = f2bf(v2[0]); hh[1] = f2bf(v2[1]); hh[2] = f2bf(v2[2]); hh[3] = f2bf(v2[3]);
        hh[4] = f2bf(v3[0]); hh[5] = f2bf(v3[1]); hh[6] = f2bf(v3[2]); hh[7] = f2bf(v3[3]);
        char* dst = db + (size_t)p * 8192 + s * 1024 + ln * 16;
        *(us8*)dst = lo;            // (kk=s, hi=0): 512B-contiguous across lanes
        *(us8*)(dst + 512) = hh;    // (kk=s, hi=1)
    }

    // norms: 8 threads/row (L1-hot re-read), 8-lane butterfly reduce
    {
        const int r = t >> 3, sub = t & 7;
        const f32x4* row = (const f32x4*)(src + (size_t)(r0 + r) * 128);
        float s = 0.f;
#pragma unroll
        for (int c = 0; c < 4; ++c) {
            f32x4 v = row[sub * 4 + c];
            s += v[0] * v[0] + v[1] * v[1] + v[2] * v[2] + v[3] * v[3];
        }
        s += __shfl_xor(s, 1);
        s += __shfl_xor(s, 2);
        s += __shfl_xor(s, 4);
        if (sub == 0) dn[r0 + r] = NLOG2E * s;
    }
}

// ---- main: NO LDS, NO barriers. Fragments loaded straight from the L2-resident
// panel arrays into registers; 32x32x16 MFMA; full-line nt stores from acc.
// ~24 waves/CU keeps the store pipe continuously fed. ----
__global__ __launch_bounds__(256, 4)
void rbf_main(const char* __restrict__ Xp, const char* __restrict__ Yp,
              const float* __restrict__ x2n, const float* __restrict__ y2n,
              float* __restrict__ O, int ldo) {
    const int t = threadIdx.x, l = t & 63, w = t >> 6;
    const int col0 = blockIdx.x * 128, row0 = blockIdx.y * 64;
    const int wr = (w >> 1) * 32, wcw = (w & 1) * 64;   // wave tile: 32 rows x 64 cols
    const int ln = l & 31, hi = l >> 5;

    const char* pa  = Xp + (size_t)((row0 + wr) >> 5) * 8192 + l * 16;
    const char* pb0 = Yp + (size_t)((col0 + wcw) >> 5) * 8192 + l * 16;
    const char* pb1 = pb0 + 8192;

    f32x4 xv[4];
#pragma unroll
    for (int g = 0; g < 4; ++g)
        xv[g] = *(const f32x4*)&x2n[row0 + wr + 8 * g + 4 * hi];
    float ynp[2];
    ynp[0] = y2n[col0 + wcw + ln];
    ynp[1] = y2n[col0 + wcw + 32 + ln];

    f32x16 acc0 = {}, acc1 = {};
#pragma unroll
    for (int kk = 0; kk < 8; ++kk) {
        bf16x8 af = *(const bf16x8*)(pa  + kk * 1024);
        bf16x8 b0 = *(const bf16x8*)(pb0 + kk * 1024);
        bf16x8 b1 = *(const bf16x8*)(pb1 + kk * 1024);
        acc0 = __builtin_amdgcn_mfma_f32_32x32x16_bf16(af, b0, acc0, 0, 0, 0);
        acc1 = __builtin_amdgcn_mfma_f32_32x32x16_bf16(af, b1, acc1, 0, 0, 0);
    }

    // epilogue: arg = 2*log2e*xy + (xn+yn), clamp <=0, exp2 -> nt store.
    // One store instr = rows {r, r+4} x 32 consecutive cols = 2 full 128B lines.
#pragma unroll
    for (int nf = 0; nf < 2; ++nf) {
        float yb = ynp[nf];
        float* ob = &O[(size_t)(row0 + wr + 4 * hi) * ldo + col0 + wcw + nf * 32 + ln];
#pragma unroll
        for (int g = 0; g < 4; ++g) {
#pragma unroll
            for (int i = 0; i < 4; ++i) {
                float xy = (nf == 0) ? acc0[g * 4 + i] : acc1[g * 4 + i];
                float arg = fmaf(TWOLOG2E, xy, xv[g][i] + yb);
                arg = fminf(arg, 0.f);
                __builtin_nontemporal_store(exp2f(arg), &ob[(size_t)(8 * g + i) * ldo]);
            }
        }
    }
}

extern "C" void kernel_launch(void* const* d_in, const int* in_sizes, int n_in,
                              void* d_out, int out_size, void* d_ws, size_t ws_size,
                              hipStream_t stream) {
    const float* X = (const float*)d_in[0];
    const float* Y = (const float*)d_in[1];
    float* O = (float*)d_out;
    const int N = in_sizes[0] / 128;          // 8192
    const int M = in_sizes[1] / 128;          // 8192
    char* Xp = (char*)d_ws;                   // N*256 B panels (2 MB)
    char* Yp = Xp + (size_t)N * 256;          // 2 MB
    float* x2n = (float*)(Yp + (size_t)M * 256);
    float* y2n = x2n + N;
    rbf_prep<<<dim3((N + M) / 32), 256, 0, stream>>>(X, Y, Xp, Yp, x2n, y2n);
    rbf_main<<<dim3(M / 128, N / 64), 256, 0, stream>>>(Xp, Yp, x2n, y2n, O, M);
}